// Round 11
// baseline (396.216 us; speedup 1.0000x reference)
//
#include <hip/hip_runtime.h>
#include <math.h>

// ---------------- constants ----------------
#define NN 512
#define CSD 384
#define CZD 128
#define HD 8
#define CD 128
#define EPSV 1e-8f
#define INFV 100000.0f

// ---------------- ws float offsets (no unions; ws is 512 MiB, we use ~60 MB) ----
#define OFF_QN    ((size_t)0)         // 2048
#define OFF_TR    ((size_t)2048)      // 1536
#define OFF_ROWT  ((size_t)4096)      // 4096
#define OFF_COLT  ((size_t)8192)      // 4096
#define OFF_SB    ((size_t)12288)     // 32768
#define OFF_QBUF  ((size_t)45056)     // 524288
#define OFF_KV    ((size_t)569344)    // 1048576
#define OFF_QPR   ((size_t)1617920)   // 98304
#define OFF_KPR   ((size_t)1716224)   // 98304
#define OFF_VGR   ((size_t)1814528)   // 65536
#define OFF_ZB    ((size_t)1880064)   // 2097152
#define OFF_A     ((size_t)3977216)   // 2097152
#define OFF_U     ((size_t)6074368)   // 655360
#define OFF_V     ((size_t)6729728)   // 655360 (stored [h][i][160], row-major)
#define OFF_VP    ((size_t)7385088)   // 1048576
#define OFF_OB0   ((size_t)8433664)   // 524288
#define OFF_OB1   ((size_t)8957952)   // 524288
#define OFF_OG0   ((size_t)9482240)   // 524288
#define OFF_OG1   ((size_t)10006528)  // 524288
#define OFF_FEATS ((size_t)10530816)  // 1277952
#define OFF_PS    ((size_t)11808768)  // 1179648 (6 x 512 x 384)
#define OFF_AZP   ((size_t)12988416)  // 2097152 (4 az partial slabs [4][512][1024])

typedef __attribute__((ext_vector_type(4))) float f32x4;
typedef __attribute__((ext_vector_type(8))) short bf16x8;
typedef __attribute__((ext_vector_type(4))) short s16x4;

__device__ __forceinline__ void qrot(const float q[4], const float* v, float* out) {
    float qw = q[0], qx = q[1], qy = q[2], qz = q[3];
    float ux = qy*v[2] - qz*v[1];
    float uy = qz*v[0] - qx*v[2];
    float uz = qx*v[1] - qy*v[0];
    float uux = qy*uz - qz*uy;
    float uuy = qz*ux - qx*uz;
    float uuz = qx*uy - qy*ux;
    out[0] = v[0] + 2.0f*(qw*ux + uux);
    out[1] = v[1] + 2.0f*(qw*uy + uuy);
    out[2] = v[2] + 2.0f*(qw*uz + uuz);
}

// fp32 -> bf16 (RNE) hi + residual lo
__device__ __forceinline__ void cvt2(float x, unsigned short& h, unsigned short& lo) {
    unsigned u = __float_as_uint(x);
    unsigned r = (u + 0x7FFFu + ((u >> 16) & 1u)) >> 16;
    h = (unsigned short)r;
    float hf = __uint_as_float(r << 16);
    float lf = x - hf;
    unsigned u2 = __float_as_uint(lf);
    unsigned r2 = (u2 + 0x7FFFu + ((u2 >> 16) & 1u)) >> 16;
    lo = (unsigned short)r2;
}

// store 4 consecutive k for one row (row-major staging), stride 40 shorts
__device__ __forceinline__ void stA(short* H, short* L, int row, int k4, float4 v) {
    unsigned short h0,l0,h1,l1,h2,l2,h3,l3;
    cvt2(v.x,h0,l0); cvt2(v.y,h1,l1); cvt2(v.z,h2,l2); cvt2(v.w,h3,l3);
    s16x4 vh = {(short)h0,(short)h1,(short)h2,(short)h3};
    s16x4 vl = {(short)l0,(short)l1,(short)l2,(short)l3};
    *(s16x4*)(H + row*40 + k4) = vh;
    *(s16x4*)(L + row*40 + k4) = vl;
}
// transposed staging: 4 consecutive n for one k
__device__ __forceinline__ void stBT(short* H, short* L, int k, int n4, float4 v) {
    unsigned short h, lo;
    cvt2(v.x,h,lo); H[(n4+0)*40+k]=(short)h; L[(n4+0)*40+k]=(short)lo;
    cvt2(v.y,h,lo); H[(n4+1)*40+k]=(short)h; L[(n4+1)*40+k]=(short)lo;
    cvt2(v.z,h,lo); H[(n4+2)*40+k]=(short)h; L[(n4+2)*40+k]=(short)lo;
    cvt2(v.w,h,lo); H[(n4+3)*40+k]=(short)h; L[(n4+3)*40+k]=(short)lo;
}

// ---------- MFMA tile core: 64x64 tile, K-step 32, 256 thr (4 waves) ----------
template<int BT>
__device__ __forceinline__ void mfma_tiles(const float* __restrict__ A, int lda,
                                           const float* __restrict__ B, int ldb,
                                           int m0, int n0, int k0, int nk,
                                           f32x4* acc,
                                           short* Ah, short* Al, short* Bh, short* Bl) {
    int t = threadIdx.x;
    int w = t >> 6, l = t & 63, g = l >> 4, li = l & 15;
    int ar = t >> 3, ak = (t & 7) << 2;
    const float* Ap0 = A + (size_t)(m0 + ar)*lda + ak;
    const float* Ap1 = A + (size_t)(m0 + ar + 32)*lda + ak;
    const float* Bp0; const float* Bp1;
    int bk = t >> 4, bn = (t & 15) << 2;
    if (BT) {
        Bp0 = B + (size_t)(n0 + ar)*ldb + ak;
        Bp1 = B + (size_t)(n0 + ar + 32)*ldb + ak;
    } else {
        Bp0 = B + (size_t)bk*ldb + n0 + bn;
        Bp1 = B + (size_t)(bk + 16)*ldb + n0 + bn;
    }
    float4 a0 = *(const float4*)(Ap0 + k0);
    float4 a1 = *(const float4*)(Ap1 + k0);
    float4 b0, b1;
    if (BT) { b0 = *(const float4*)(Bp0 + k0); b1 = *(const float4*)(Bp1 + k0); }
    else    { b0 = *(const float4*)(Bp0 + (size_t)k0*ldb); b1 = *(const float4*)(Bp1 + (size_t)k0*ldb); }
    for (int kc = 0; kc < nk; kc++) {
        stA(Ah, Al, ar, ak, a0);
        stA(Ah, Al, ar+32, ak, a1);
        if (BT) { stA(Bh, Bl, ar, ak, b0); stA(Bh, Bl, ar+32, ak, b1); }
        else    { stBT(Bh, Bl, bk, bn, b0); stBT(Bh, Bl, bk+16, bn, b1); }
        __syncthreads();
        if (kc + 1 < nk) {
            int kb = k0 + (kc+1)*32;
            a0 = *(const float4*)(Ap0 + kb);
            a1 = *(const float4*)(Ap1 + kb);
            if (BT) { b0 = *(const float4*)(Bp0 + kb); b1 = *(const float4*)(Bp1 + kb); }
            else { b0 = *(const float4*)(Bp0 + (size_t)kb*ldb); b1 = *(const float4*)(Bp1 + (size_t)kb*ldb); }
        }
        int arow = (w*16 + li)*40 + g*8;
        bf16x8 avh = *(bf16x8*)(Ah + arow);
        bf16x8 avl = *(bf16x8*)(Al + arow);
        #pragma unroll
        for (int c = 0; c < 4; c++) {
            int brow = (c*16 + li)*40 + g*8;
            bf16x8 bvh = *(bf16x8*)(Bh + brow);
            bf16x8 bvl = *(bf16x8*)(Bl + brow);
            acc[c] = __builtin_amdgcn_mfma_f32_16x16x32_bf16(avh, bvh, acc[c], 0, 0, 0);
            acc[c] = __builtin_amdgcn_mfma_f32_16x16x32_bf16(avh, bvl, acc[c], 0, 0, 0);
            acc[c] = __builtin_amdgcn_mfma_f32_16x16x32_bf16(avl, bvh, acc[c], 0, 0, 0);
        }
        __syncthreads();
    }
}

// ---------- VALU tiled-GEMM core (k_proj_all / k_sout) ----------
__device__ __forceinline__ void gemm_tiles(const float* __restrict__ A, int lda,
                                           const float* __restrict__ B, int ldb,
                                           int m0, int n0, int k0, int nk,
                                           float acc[4][4], float* AsT, float* Bs) {
    int t = threadIdx.x;
    int tx = t & 15, ty = t >> 4;
    int arow = t >> 3, ak4 = (t & 7) << 2;
    int brow = t >> 4, bc4 = (t & 15) << 2;
    const float* Ap0 = A + (size_t)(m0 + arow)*lda + ak4;
    const float* Ap1 = A + (size_t)(m0 + arow + 32)*lda + ak4;
    const float* Bp0 = B + (size_t)brow*ldb + n0 + bc4;
    const float* Bp1 = B + (size_t)(brow + 16)*ldb + n0 + bc4;
    float4 a0 = *(const float4*)(Ap0 + k0);
    float4 a1 = *(const float4*)(Ap1 + k0);
    float4 b0 = *(const float4*)(Bp0 + (size_t)k0*ldb);
    float4 b1 = *(const float4*)(Bp1 + (size_t)k0*ldb);
    for (int kc = 0; kc < nk; kc++) {
        AsT[(ak4+0)*68 + arow] = a0.x;
        AsT[(ak4+1)*68 + arow] = a0.y;
        AsT[(ak4+2)*68 + arow] = a0.z;
        AsT[(ak4+3)*68 + arow] = a0.w;
        AsT[(ak4+0)*68 + arow+32] = a1.x;
        AsT[(ak4+1)*68 + arow+32] = a1.y;
        AsT[(ak4+2)*68 + arow+32] = a1.z;
        AsT[(ak4+3)*68 + arow+32] = a1.w;
        *(float4*)(Bs + brow*64 + bc4) = b0;
        *(float4*)(Bs + (brow+16)*64 + bc4) = b1;
        __syncthreads();
        if (kc + 1 < nk) {
            int kb = k0 + (kc+1)*32;
            a0 = *(const float4*)(Ap0 + kb);
            a1 = *(const float4*)(Ap1 + kb);
            b0 = *(const float4*)(Bp0 + (size_t)kb*ldb);
            b1 = *(const float4*)(Bp1 + (size_t)kb*ldb);
        }
        #pragma unroll
        for (int kk = 0; kk < 32; kk++) {
            float4 av = *(const float4*)(AsT + kk*68 + ty*4);
            float4 bv = *(const float4*)(Bs + kk*64 + tx*4);
            acc[0][0] += av.x*bv.x; acc[0][1] += av.x*bv.y; acc[0][2] += av.x*bv.z; acc[0][3] += av.x*bv.w;
            acc[1][0] += av.y*bv.x; acc[1][1] += av.y*bv.y; acc[1][2] += av.y*bv.z; acc[1][3] += av.y*bv.w;
            acc[2][0] += av.z*bv.x; acc[2][1] += av.z*bv.y; acc[2][2] += av.z*bv.z; acc[2][3] += av.z*bv.w;
            acc[3][0] += av.w*bv.x; acc[3][1] += av.w*bv.y; acc[3][2] += av.w*bv.z; acc[3][3] += av.w*bv.w;
        }
        __syncthreads();
    }
}

// ---------------- kernels ----------------

__global__ __launch_bounds__(256) void k_proj_all(const float* __restrict__ s,
    const float* __restrict__ W_q,  const float* __restrict__ b_q,  float* __restrict__ qbuf,
    const float* __restrict__ W_kv, const float* __restrict__ b_kv, float* __restrict__ kvb,
    const float* __restrict__ W_qp, const float* __restrict__ b_qp, float* __restrict__ qpr,
    const float* __restrict__ W_kp, const float* __restrict__ b_kp, float* __restrict__ kpr,
    const float* __restrict__ W_vg, const float* __restrict__ b_vg, float* __restrict__ vgr) {
    __shared__ float AsT[32*68];
    __shared__ float Bs[32*64];
    int ny = blockIdx.y;
    const float* W; const float* bias; float* C; int N; int n0;
    if (ny < 16)      { W=W_q;  bias=b_q;  C=qbuf; N=1024; n0=ny*64; }
    else if (ny < 48) { W=W_kv; bias=b_kv; C=kvb;  N=2048; n0=(ny-16)*64; }
    else if (ny < 51) { W=W_qp; bias=b_qp; C=qpr;  N=192;  n0=(ny-48)*64; }
    else if (ny < 54) { W=W_kp; bias=b_kp; C=kpr;  N=192;  n0=(ny-51)*64; }
    else              { W=W_vg; bias=b_vg; C=vgr;  N=128;  n0=(ny-54)*64; }
    int m0 = blockIdx.x*64;
    float acc[4][4] = {};
    gemm_tiles(s, CSD, W, N, m0, n0, 0, 12, acc, AsT, Bs);
    int tx = threadIdx.x & 15, ty = threadIdx.x >> 4;
    float4 bb = *(const float4*)(bias + n0 + tx*4);
    #pragma unroll
    for (int rr = 0; rr < 4; rr++) {
        float4 o = make_float4(acc[rr][0]+bb.x, acc[rr][1]+bb.y, acc[rr][2]+bb.z, acc[rr][3]+bb.w);
        *(float4*)(C + (size_t)(m0+ty*4+rr)*N + n0 + tx*4) = o;
    }
}

// fused: prep + q-points + k-points + vg + uv + Vp-pack. One block per residue n.
__global__ __launch_bounds__(256) void k_geo(
    const float* __restrict__ T,
    const float* __restrict__ qpr, const float* __restrict__ kpr,
    const float* __restrict__ vgr, const float* __restrict__ g,
    const float* __restrict__ W_mg,
    const float* __restrict__ qbuf, const float* __restrict__ kvb,
    const float* __restrict__ hwraw, const float* __restrict__ b_b,
    float* __restrict__ qn, float* __restrict__ tr,
    float* __restrict__ U, float* __restrict__ V,
    float* __restrict__ rowt, float* __restrict__ colt,
    float* __restrict__ Vp)
{
    __shared__ float s_q[4];
    __shared__ float s_t[3];
    __shared__ float s_qpts[192], s_kpts[192];
    __shared__ float s_Qsq[8], s_Ksq[8];
    int n = blockIdx.x, t = threadIdx.x;
    if (t == 0) {
        float q0=T[n*16+0], q1=T[n*16+1], q2=T[n*16+2], q3=T[n*16+3];
        float inv = 1.0f/sqrtf(q0*q0+q1*q1+q2*q2+q3*q3 + EPSV);
        float a0=q0*inv, a1=q1*inv, a2=q2*inv, a3=q3*inv;
        s_q[0]=a0; s_q[1]=a1; s_q[2]=a2; s_q[3]=a3;
        float u0=T[n*16+4], u1=T[n*16+5], u2=T[n*16+6];
        s_t[0]=u0; s_t[1]=u1; s_t[2]=u2;
        qn[n*4+0]=a0; qn[n*4+1]=a1; qn[n*4+2]=a2; qn[n*4+3]=a3;
        tr[n*3+0]=u0; tr[n*3+1]=u1; tr[n*3+2]=u2;
    }
    __syncthreads();
    float q[4]={s_q[0],s_q[1],s_q[2],s_q[3]};
    float t0=s_t[0], t1=s_t[1], t2=s_t[2];
    if (t < 128) {
        int m = t & 63;
        const float* raw = (t < 64) ? qpr : kpr;
        float p[3] = {raw[n*192 + m], raw[n*192 + 64 + m], raw[n*192 + 128 + m]};
        float r[3]; qrot(q,p,r);
        r[0]+=t0; r[1]+=t1; r[2]+=t2;
        float* dp = (t<64) ? s_qpts : s_kpts;
        dp[m*3+0]=r[0]; dp[m*3+1]=r[1]; dp[m*3+2]=r[2];
        float ss = r[0]*r[0]+r[1]*r[1]+r[2]*r[2];
        ss += __shfl_down(ss,4,8);
        ss += __shfl_down(ss,2,8);
        ss += __shfl_down(ss,1,8);
        if ((m&7)==0) ((t<64)?s_Qsq:s_Ksq)[m>>3] = ss;
    } else if (t < 192) {
        int o = t - 128;
        float in[16];
        #pragma unroll
        for (int c=0;c<16;c++){
            float acc=0.0f;
            #pragma unroll
            for (int i=0;i<8;i++)  acc += W_mg[o*16+i]*vgr[n*128+i*16+c];
            #pragma unroll
            for (int i=8;i<16;i++) acc += W_mg[o*16+i]*g[n*128+(i-8)*16+c];
            in[c]=acc;
        }
        float out[16];
        out[0]=in[0];
        qrot(q,in+1,out+1);
        qrot(q,in+4,out+4);
        float w=in[10];
        qrot(q,in+7,out+7);
        out[7]+=w*t0; out[8]+=w*t1; out[9]+=w*t2;
        #pragma unroll
        for (int c=10;c<16;c++) out[c]=in[c];
        int h=o>>3, pp=o&7;
        float* vp = Vp + ((size_t)(h*512+n))*256 + 128 + pp*16;
        #pragma unroll
        for (int c=0;c<16;c++) vp[c]=out[c];
    }
    #pragma unroll
    for (int l=0;l<4;l++){
        int f = t + l*256; int h = f>>7, c = f&127;
        Vp[((size_t)(h*512+n))*256 + c] = kvb[(size_t)n*2048 + h*256 + 128 + c];
    }
    __syncthreads();
    #pragma unroll
    for (int h = 0; h < 8; h++) {
        float hwv = log1pf(expf(hwraw[h])) * 0.09622504486493763f; // softplus * sqrt(1/108)
        if (t < 160) {
            float u, v;
            if (t < 128) {
                u = 0.05103103630798287f * qbuf[(size_t)n*1024 + h*128 + t]; // sqrt(1/384)
                v = kvb[(size_t)n*2048 + h*256 + t];
            } else if (t < 152) {
                int d = t - 128;
                u = hwv * s_qpts[h*24 + d];
                v = s_kpts[h*24 + d];
            } else { u = 0.0f; v = 0.0f; }
            U[((size_t)h*512 + n)*160 + t] = u;
            V[((size_t)h*512 + n)*160 + t] = v;   // row-major
        }
        if (t == 160) rowt[h*512+n] = -0.5f*hwv*s_Qsq[h] + 0.5773502691896258f*b_b[h] - INFV;
        if (t == 161) colt[h*512+n] = -0.5f*hwv*s_Ksq[h];
    }
}

// zb[h][i][j] = sum_c z[i,j,c] * W_b[c,h]
// v3: 16-lane group per j-row, weights in registers, 32B/lane coalesced reads,
// no LDS, grid (512,4)x256.
__global__ __launch_bounds__(256) void k_zb(const float* __restrict__ z,
        const float* __restrict__ W_b, float* __restrict__ zb) {
    int i = blockIdx.x, j0 = blockIdx.y*128;
    int t = threadIdx.x, w = t>>6, l = t&63;
    int gp = l>>4, k = l&15;
    float wb[8][8];
    #pragma unroll
    for (int cc=0;cc<8;cc++){
        float4 w0 = *(const float4*)(W_b + (k*8+cc)*8);
        float4 w1 = *(const float4*)(W_b + (k*8+cc)*8 + 4);
        wb[cc][0]=w0.x; wb[cc][1]=w0.y; wb[cc][2]=w0.z; wb[cc][3]=w0.w;
        wb[cc][4]=w1.x; wb[cc][5]=w1.y; wb[cc][6]=w1.z; wb[cc][7]=w1.w;
    }
    for (int it = 0; it < 8; it++) {
        int j = j0 + it*16 + w*4 + gp;
        const float* zp = z + ((size_t)i*512 + j)*128 + k*8;
        float4 za = *(const float4*)(zp);
        float4 zb4 = *(const float4*)(zp + 4);
        float zz[8] = {za.x,za.y,za.z,za.w,zb4.x,zb4.y,zb4.z,zb4.w};
        float acc[8];
        #pragma unroll
        for (int h=0;h<8;h++) acc[h] = zz[0]*wb[0][h];
        #pragma unroll
        for (int cc=1;cc<8;cc++)
            #pragma unroll
            for (int h=0;h<8;h++) acc[h] += zz[cc]*wb[cc][h];
        #pragma unroll
        for (int h=0;h<8;h++) {
            acc[h] += __shfl_xor(acc[h], 1);
            acc[h] += __shfl_xor(acc[h], 2);
            acc[h] += __shfl_xor(acc[h], 4);
            acc[h] += __shfl_xor(acc[h], 8);
        }
        float outv = acc[0];
        #pragma unroll
        for (int h=1;h<8;h++) if (k == h) outv = acc[h];
        if (k < 8) zb[((size_t)k*512 + i)*512 + j] = outv;
    }
}

// raw scores via K=160 MFMA GEMM + affine epilogue
__global__ __launch_bounds__(256) void k_scorefill(const float* __restrict__ U, const float* __restrict__ V,
        const float* __restrict__ rowt, const float* __restrict__ colt,
        const float* __restrict__ zb, const float* __restrict__ mask,
        const float* __restrict__ sw, float* __restrict__ Am) {
    __shared__ short Ah[64*40], Al[64*40], Bh[64*40], Bl[64*40];
    int h = blockIdx.z;
    int m0 = blockIdx.x*64, n0 = blockIdx.y*64;
    f32x4 acc[4] = {};
    mfma_tiles<1>(U + (size_t)h*512*160, 160, V + (size_t)h*512*160, 160,
                  m0, n0, 0, 5, acc, Ah, Al, Bh, Bl);
    int t = threadIdx.x, w = t >> 6, l = t & 63, g = l >> 4, li = l & 15;
    float swh = sw[h];
    #pragma unroll
    for (int c = 0; c < 4; c++) {
        int j = n0 + c*16 + li;
        float ct = colt[h*512 + j];
        float mj = mask[j];
        #pragma unroll
        for (int r = 0; r < 4; r++) {
            int i = m0 + w*16 + g*4 + r;
            float rt = rowt[h*512 + i];
            float mi = mask[i]*INFV;
            float zv = zb[((size_t)h*512 + i)*512 + j];
            Am[((size_t)h*512 + i)*512 + j] =
                (acc[c][r] + rt + ct + 0.5773502691896258f*zv + mi*mj)*swh;
        }
    }
}

// softmax over each (h,i) row, in-place; fuses the S-moments (o_rel reduction)
__global__ __launch_bounds__(256) void k_softmax(float* __restrict__ Am,
        const float* __restrict__ qn, const float* __restrict__ tr, float* __restrict__ S) {
    __shared__ float red[8];
    __shared__ float sred[4][8];
    int row = blockIdx.x;           // h*512 + i
    float* p = Am + (size_t)row*512;
    int t = threadIdx.x;            // 256
    float x0 = p[t], x1 = p[t+256];
    float m = fmaxf(x0, x1);
    #pragma unroll
    for (int o = 32; o > 0; o >>= 1) m = fmaxf(m, __shfl_xor(m, o));
    int wv = t >> 6, ln = t & 63;
    if (ln == 0) red[wv] = m;
    __syncthreads();
    m = fmaxf(fmaxf(red[0], red[1]), fmaxf(red[2], red[3]));
    float e0 = expf(x0 - m), e1 = expf(x1 - m);
    float sm = e0 + e1;
    #pragma unroll
    for (int o = 32; o > 0; o >>= 1) sm += __shfl_xor(sm, o);
    __syncthreads();
    if (ln == 0) red[4 + wv] = sm;
    __syncthreads();
    float inv = 1.0f / (red[4]+red[5]+red[6]+red[7]);
    float a0 = e0*inv, a1 = e1*inv;
    p[t] = a0;
    p[t+256] = a1;
    float4 q0 = *(const float4*)(qn + t*4);
    float4 q1 = *(const float4*)(qn + (t+256)*4);
    float acc[8];
    acc[0] = a0*q0.x + a1*q1.x;
    acc[1] = a0*q0.y + a1*q1.y;
    acc[2] = a0*q0.z + a1*q1.z;
    acc[3] = a0*q0.w + a1*q1.w;
    acc[4] = a0*tr[t*3+0] + a1*tr[(t+256)*3+0];
    acc[5] = a0*tr[t*3+1] + a1*tr[(t+256)*3+1];
    acc[6] = a0*tr[t*3+2] + a1*tr[(t+256)*3+2];
    acc[7] = a0 + a1;
    #pragma unroll
    for (int c = 0; c < 8; c++) {
        #pragma unroll
        for (int o = 32; o > 0; o >>= 1) acc[c] += __shfl_xor(acc[c], o);
    }
    if (ln == 0) {
        #pragma unroll
        for (int c = 0; c < 8; c++) sred[wv][c] = acc[c];
    }
    __syncthreads();
    if (t < 8) {
        int h = row >> 9, i = row & 511;
        S[i*64 + h*8 + t] = sred[0][t]+sred[1][t]+sred[2][t]+sred[3][t];
    }
}

// az partials: azp[jq][i][h][c] = sum_{j in quarter} a[h,i,j]*z[i,j,c]
// grid (512,4): 2048 blocks, 18 KB LDS -> 8 blocks/CU. Fixes the 2-blocks/CU
// latency-bound second z pass that lived inside k_azfin.
__global__ __launch_bounds__(256) void k_az(
        const float* __restrict__ Am, const float* __restrict__ z,
        float* __restrict__ azp) {
    __shared__ float aT[128*12];    // [j][12], h in 0..7, 48B rows
    __shared__ float part[3*1024];
    int i = blockIdx.x, jq = blockIdx.y, j0 = jq*128;
    int t = threadIdx.x;
    #pragma unroll
    for (int l2 = 0; l2 < 4; l2++) {
        int f = t + l2*256;         // 0..1023
        int h = f >> 7, jl = f & 127;
        aT[jl*12 + h] = Am[((size_t)h*512 + i)*512 + j0 + jl];
    }
    __syncthreads();
    int c2 = t & 63, sub = t >> 6;
    int jb = sub*32;
    float acc[8][2] = {};
    for (int jo = 0; jo < 32; jo++) {
        int j = jb + jo;
        float2 zv = *(const float2*)(z + ((size_t)i*512 + j0 + j)*128 + c2*2);
        float4 a0 = *(const float4*)(aT + j*12);
        float4 a1 = *(const float4*)(aT + j*12 + 4);
        acc[0][0] += a0.x*zv.x; acc[0][1] += a0.x*zv.y;
        acc[1][0] += a0.y*zv.x; acc[1][1] += a0.y*zv.y;
        acc[2][0] += a0.z*zv.x; acc[2][1] += a0.z*zv.y;
        acc[3][0] += a0.w*zv.x; acc[3][1] += a0.w*zv.y;
        acc[4][0] += a1.x*zv.x; acc[4][1] += a1.x*zv.y;
        acc[5][0] += a1.y*zv.x; acc[5][1] += a1.y*zv.y;
        acc[6][0] += a1.z*zv.x; acc[6][1] += a1.z*zv.y;
        acc[7][0] += a1.w*zv.x; acc[7][1] += a1.w*zv.y;
    }
    if (sub > 0) {
        #pragma unroll
        for (int h = 0; h < 8; h++) {
            part[(sub-1)*1024 + h*128 + c2*2 + 0] = acc[h][0];
            part[(sub-1)*1024 + h*128 + c2*2 + 1] = acc[h][1];
        }
    }
    __syncthreads();
    if (sub == 0) {
        float* dst = azp + ((size_t)jq*512 + i)*1024;
        #pragma unroll
        for (int h = 0; h < 8; h++) {
            #pragma unroll
            for (int d = 0; d < 2; d++) {
                dst[h*128 + c2*2 + d] = acc[h][d] + part[h*128 + c2*2 + d]
                          + part[1024 + h*128 + c2*2 + d] + part[2048 + h*128 + c2*2 + d];
            }
        }
    }
}

// o and o_g via MFMA GEMM: per js in {0,1}, non-atomic stores into separate slabs.
__global__ __launch_bounds__(256) void k_apply(const float* __restrict__ Am,
        const float* __restrict__ Vp, float* __restrict__ ob0, float* __restrict__ ob1,
        float* __restrict__ og0, float* __restrict__ og1) {
    __shared__ short Ah[64*40], Al[64*40], Bh[64*40], Bl[64*40];
    int m0 = blockIdx.x*64;             // i tile
    int n0 = blockIdx.y*64;             // col tile (0..255)
    int h = blockIdx.z & 7, js = blockIdx.z >> 3;
    f32x4 acc[4] = {};
    mfma_tiles<0>(Am + (size_t)h*512*512, 512, Vp + (size_t)h*512*256, 256,
                  m0, n0, js*256, 8, acc, Ah, Al, Bh, Bl);
    int t = threadIdx.x, w = t >> 6, l = t & 63, g = l >> 4, li = l & 15;
    float* obuf = js ? ob1 : ob0;
    float* og   = js ? og1 : og0;
    #pragma unroll
    for (int c = 0; c < 4; c++) {
        int col = n0 + c*16 + li;
        float* base = (col < 128) ? (obuf + h*128 + col) : (og + h*128 + col - 128);
        #pragma unroll
        for (int r = 0; r < 4; r++) {
            int i = m0 + w*16 + g*4 + r;
            base[(size_t)i*1024] = acc[c][r];
        }
    }
}

// fused: az-slab sum + finalize + gout. One block per residue i, 256 threads.
__global__ __launch_bounds__(256) void k_azfin(
    const float* __restrict__ azp,
    const float* __restrict__ ob0, const float* __restrict__ ob1,
    const float* __restrict__ og0, const float* __restrict__ og1,
    const float* __restrict__ W_dz, const float* __restrict__ b_dz,
    const float* __restrict__ S, const float* __restrict__ qn, const float* __restrict__ tr,
    const float* __restrict__ W_geo,
    float* __restrict__ feats, float* __restrict__ outg)
{
    __shared__ float s_az[1024];    // [h][128]
    __shared__ float s_og[1024];    // [(h*8+p)][16], post-transform
    int i = blockIdx.x, t = threadIdx.x;
    #pragma unroll
    for (int l2 = 0; l2 < 4; l2++) {
        int c = t + l2*256;         // 0..1023  (same summation order as fused version)
        s_az[c] = azp[((size_t)0*512 + i)*1024 + c] + azp[((size_t)1*512 + i)*1024 + c]
                + azp[((size_t)2*512 + i)*1024 + c] + azp[((size_t)3*512 + i)*1024 + c];
    }
    __syncthreads();
    float* f = feats + (size_t)i*2496;
    #pragma unroll
    for (int l = 0; l < 4; l++) {
        int ff = t + l*256; int h = ff>>7, c = ff&127;
        f[h*312 + 32 + c] = ob0[(size_t)i*1024 + h*128 + c] + ob1[(size_t)i*1024 + h*128 + c];
    }
    {
        int h = t >> 5, cdz = t & 31;
        float a2 = b_dz[cdz];
        #pragma unroll 4
        for (int zc = 0; zc < 128; zc++) a2 += s_az[h*128 + zc]*W_dz[zc*32 + cdz];
        f[h*312 + cdz] = a2;
    }
    float qc0=qn[i*4], qc1=-qn[i*4+1], qc2=-qn[i*4+2], qc3=-qn[i*4+3];
    float t0=tr[i*3], t1=tr[i*3+1], t2=tr[i*3+2];
    if (t < 64) {
        int h = t >> 3, p = t & 7;
        const float* a0 = og0 + (size_t)i*1024 + h*128 + p*16;
        const float* a1 = og1 + (size_t)i*1024 + h*128 + p*16;
        float in[16];
        #pragma unroll
        for (int c=0;c<16;c++) in[c]=a0[c]+a1[c];
        float qc[4]={qc0,qc1,qc2,qc3};
        float out[16];
        out[0]=in[0];
        qrot(qc,in+1,out+1);
        qrot(qc,in+4,out+4);
        float w=in[10];
        float tmp[3]={in[7]-w*t0, in[8]-w*t1, in[9]-w*t2};
        qrot(qc,tmp,out+7);
        #pragma unroll
        for (int c2x=10;c2x<16;c2x++) out[c2x]=in[c2x];
        float n1=EPSV, n2=EPSV;
        #pragma unroll
        for (int c2x=0;c2x<10;c2x++) n1 += out[c2x]*out[c2x];
        #pragma unroll
        for (int c2x=10;c2x<16;c2x++) n2 += out[c2x]*out[c2x];
        n1=sqrtf(n1); n2=sqrtf(n2);
        #pragma unroll
        for (int c2x=0;c2x<16;c2x++){ f[h*312+168+p*16+c2x]=out[c2x]; s_og[t*16+c2x]=out[c2x]; }
        f[h*312+296+p*2]=n1; f[h*312+296+p*2+1]=n2;
    } else if (t < 72) {
        int h = t - 64;
        const float* Sr = S + i*64 + h*8;
        float b0=Sr[0], b1=Sr[1], b2=Sr[2], b3=Sr[3];
        f[h*312+160] = qc0*b0 - qc1*b1 - qc2*b2 - qc3*b3;
        f[h*312+161] = qc0*b1 + qc1*b0 + qc2*b3 - qc3*b2;
        f[h*312+162] = qc0*b2 - qc1*b3 + qc2*b0 + qc3*b1;
        f[h*312+163] = qc0*b3 + qc1*b2 - qc2*b1 + qc3*b0;
        float A = Sr[7];
        float v[3]={Sr[4]-A*t0, Sr[5]-A*t1, Sr[6]-A*t2};
        float qc[4]={qc0,qc1,qc2,qc3};
        float r[3]; qrot(qc,v,r);
        f[h*312+164]=r[0]; f[h*312+165]=r[1]; f[h*312+166]=r[2]; f[h*312+167]=0.0f;
    }
    __syncthreads();
    if (t < 128) {
        int o = (t>>4) & 7, c = t & 15;
        float a3 = 0.0f;
        #pragma unroll 4
        for (int i2=0;i2<64;i2++) a3 += W_geo[o*64+i2]*s_og[i2*16+c];
        outg[(size_t)i*128 + o*16 + c] = a3;
    }
}

// s_out: split-K tiled GEMM into 6 non-atomic slabs
__global__ __launch_bounds__(256) void k_sout(const float* __restrict__ feats,
        const float* __restrict__ W_out, float* __restrict__ Ps) {
    __shared__ float AsT[32*68];
    __shared__ float Bs[32*64];
    int m0 = blockIdx.x*64, n0 = blockIdx.y*64, kz = blockIdx.z;
    float acc[4][4] = {};
    gemm_tiles(feats, 2496, W_out, CSD, m0, n0, kz*416, 13, acc, AsT, Bs);
    int tx = threadIdx.x & 15, ty = threadIdx.x >> 4;
    float* slab = Ps + (size_t)kz*512*384;
    #pragma unroll
    for (int rr = 0; rr < 4; rr++) {
        *(float4*)(slab + (size_t)(m0+ty*4+rr)*CSD + n0 + tx*4) =
            make_float4(acc[rr][0], acc[rr][1], acc[rr][2], acc[rr][3]);
    }
}

// reduce the 6 slabs + bias -> out
__global__ __launch_bounds__(256) void k_sout_red(const float* __restrict__ Ps,
        const float* __restrict__ b_out, float* __restrict__ out) {
    int idx = (blockIdx.x*256 + threadIdx.x)*4;   // 196608 floats total
    float4 s = *(const float4*)(b_out + (idx % 384));
    #pragma unroll
    for (int kz = 0; kz < 6; kz++) {
        float4 p = *(const float4*)(Ps + (size_t)kz*196608 + idx);
        s.x += p.x; s.y += p.y; s.z += p.z; s.w += p.w;
    }
    *(float4*)(out + idx) = s;
}

// ---------------- launch ----------------

extern "C" void kernel_launch(void* const* d_in, const int* in_sizes, int n_in,
                              void* d_out, int out_size, void* d_ws, size_t ws_size,
                              hipStream_t stream) {
    const float* s     = (const float*)d_in[0];
    const float* g     = (const float*)d_in[1];
    const float* z     = (const float*)d_in[2];
    const float* T     = (const float*)d_in[3];
    const float* mask  = (const float*)d_in[4];
    const float* W_q   = (const float*)d_in[5];
    const float* b_q   = (const float*)d_in[6];
    const float* W_kv  = (const float*)d_in[7];
    const float* b_kv  = (const float*)d_in[8];
    const float* W_qp  = (const float*)d_in[9];
    const float* b_qp  = (const float*)d_in[10];
    const float* W_kp  = (const float*)d_in[11];
    const float* b_kp  = (const float*)d_in[12];
    const float* W_vg  = (const float*)d_in[13];
    const float* b_vg  = (const float*)d_in[14];
    const float* W_mg  = (const float*)d_in[15];
    const float* W_b   = (const float*)d_in[16];
    const float* b_b   = (const float*)d_in[17];
    const float* W_dz  = (const float*)d_in[18];
    const float* b_dz  = (const float*)d_in[19];
    const float* hw    = (const float*)d_in[20];
    const float* sw    = (const float*)d_in[21];
    const float* W_out = (const float*)d_in[22];
    const float* b_out = (const float*)d_in[23];
    const float* W_geo = (const float*)d_in[24];

    float* ws   = (float*)d_ws;
    float* out  = (float*)d_out;

    float* qn   = ws + OFF_QN;
    float* tr   = ws + OFF_TR;
    float* rowt = ws + OFF_ROWT;
    float* colt = ws + OFF_COLT;
    float* Sbuf = ws + OFF_SB;
    float* qbuf = ws + OFF_QBUF;
    float* kvb  = ws + OFF_KV;
    float* qpr  = ws + OFF_QPR;
    float* kpr  = ws + OFF_KPR;
    float* vgr  = ws + OFF_VGR;
    float* zb   = ws + OFF_ZB;
    float* Am   = ws + OFF_A;
    float* U    = ws + OFF_U;
    float* V    = ws + OFF_V;
    float* Vp   = ws + OFF_VP;
    float* ob0  = ws + OFF_OB0;
    float* ob1  = ws + OFF_OB1;
    float* og0  = ws + OFF_OG0;
    float* og1  = ws + OFF_OG1;
    float* feats= ws + OFF_FEATS;
    float* Ps   = ws + OFF_PS;
    float* azp  = ws + OFF_AZP;

    k_proj_all<<<dim3(8,56),256,0,stream>>>(s, W_q,b_q,qbuf, W_kv,b_kv,kvb,
                                            W_qp,b_qp,qpr, W_kp,b_kp,kpr, W_vg,b_vg,vgr);
    k_geo<<<NN,256,0,stream>>>(T,qpr,kpr,vgr,g,W_mg,qbuf,kvb,hw,b_b,
                               qn,tr,U,V,rowt,colt,Vp);
    k_zb<<<dim3(512,4),256,0,stream>>>(z,W_b,zb);
    k_scorefill<<<dim3(8,8,8),256,0,stream>>>(U,V,rowt,colt,zb,mask,sw,Am);
    k_softmax<<<4096,256,0,stream>>>(Am,qn,tr,Sbuf);
    k_az<<<dim3(512,4),256,0,stream>>>(Am,z,azp);
    k_apply<<<dim3(8,4,16),256,0,stream>>>(Am,Vp,ob0,ob1,og0,og1);
    k_azfin<<<NN,256,0,stream>>>(azp,ob0,ob1,og0,og1,W_dz,b_dz,Sbuf,qn,tr,W_geo,
                                 feats, out + (size_t)NN*CSD);
    k_sout<<<dim3(8,6,6),256,0,stream>>>(feats,W_out,Ps);
    k_sout_red<<<192,256,0,stream>>>(Ps,b_out,out);
}